// Round 3
// baseline (399.581 us; speedup 1.0000x reference)
//
#include <hip/hip_runtime.h>
#include <hip/hip_bf16.h>
#include <stdint.h>

#define D_MODEL 1024
#define HEADS   16
#define DK      64
#define BATCH   4
#define SEQ     2048
#define MROWS   (BATCH * SEQ)  // 8192

typedef __attribute__((ext_vector_type(8))) short bf16x8;
typedef __attribute__((ext_vector_type(4))) float f32x4;
typedef __attribute__((ext_vector_type(4))) unsigned int u32x4;
typedef __attribute__((ext_vector_type(2))) unsigned int u32x2;

__device__ __forceinline__ unsigned short f2bf(float f) {
  union { float f; unsigned int u; } c; c.f = f;
  return (unsigned short)((c.u + 0x7fffu + ((c.u >> 16) & 1u)) >> 16);  // RNE
}

__device__ __forceinline__ void gl_lds16(const void* g, void* l) {
  __builtin_amdgcn_global_load_lds(
      (const __attribute__((address_space(1))) unsigned int*)g,
      (__attribute__((address_space(3))) unsigned int*)l, 16, 0, 0);
}

// ---------------- weight fp32 -> bf16 convert: all 4 matrices, one launch ----------------
__global__ __launch_bounds__(256) void cvt4(const float* __restrict__ w0, const float* __restrict__ w1,
                                            const float* __restrict__ w2, const float* __restrict__ w3,
                                            unsigned short* __restrict__ o0, unsigned short* __restrict__ o1,
                                            unsigned short* __restrict__ o2, unsigned short* __restrict__ o3) {
  const int which = blockIdx.x >> 10;
  const float* in; unsigned short* out;
  if (which == 0)      { in = w0; out = o0; }
  else if (which == 1) { in = w1; out = o1; }
  else if (which == 2) { in = w2; out = o2; }
  else                 { in = w3; out = o3; }
  const int i = ((blockIdx.x & 1023) * 256 + threadIdx.x) * 4;
  f32x4 v = *(const f32x4*)(in + i);
  u32x2 w;
  w[0] = f2bf(v[0]) | ((unsigned)f2bf(v[1]) << 16);
  w[1] = f2bf(v[2]) | ((unsigned)f2bf(v[3]) << 16);
  *(u32x2*)(out + i) = w;
}

// ---------------- GEMM: Y[M,N] = X[M,K] @ W[N,K]^T + b ----------------
// A_FP32: A operand is fp32 (reg-staged + cvt into padded LDS); else bf16 via global_load_lds.
// OUT_MODE: 0 = bf16 row-major [M,1024]; 1 = fp32 row-major (d_out);
//           2 = bf16 transposed per head: Vt_g[b][h][d][s]  (for attention V)
template <int A_FP32, int OUT_MODE>
__global__ __launch_bounds__(256) void gemm128(const void* __restrict__ Ap,
                                               const unsigned short* __restrict__ Bw,
                                               const float* __restrict__ bias,
                                               void* __restrict__ Outp) {
  constexpr int ASTR = A_FP32 ? 40 : 32;
  __shared__ unsigned short As[128 * ASTR];
  __shared__ unsigned short Bs[128 * 32];

  const int tid = threadIdx.x;
  const int lane = tid & 63, wid = tid >> 6;
  const int l16 = lane & 15, lg = lane >> 4;
  const int wrow = (wid >> 1) * 64, wcol = (wid & 1) * 64;

  const int bx = blockIdx.x;
  const int swz = (bx & 7) * 64 + (bx >> 3);
  const int m0 = (swz >> 3) * 128, n0 = (swz & 7) * 128;

  f32x4 acc[4][4];
  const f32x4 zero = {0.f, 0.f, 0.f, 0.f};
#pragma unroll
  for (int i = 0; i < 4; ++i)
#pragma unroll
    for (int j = 0; j < 4; ++j) acc[i][j] = zero;

#pragma unroll 1
  for (int kt = 0; kt < D_MODEL / 32; ++kt) {
    const int k0 = kt * 32;
    __syncthreads();
    if constexpr (A_FP32) {
      const float* Af = (const float*)Ap;
      const int ar = tid >> 1, ah = (tid & 1) * 16;
      const float* src = Af + (size_t)(m0 + ar) * D_MODEL + k0 + ah;
      f32x4 v0 = *(const f32x4*)src;
      f32x4 v1 = *(const f32x4*)(src + 4);
      f32x4 v2 = *(const f32x4*)(src + 8);
      f32x4 v3 = *(const f32x4*)(src + 12);
      u32x4 pa, pb;
      pa[0] = f2bf(v0[0]) | ((unsigned)f2bf(v0[1]) << 16);
      pa[1] = f2bf(v0[2]) | ((unsigned)f2bf(v0[3]) << 16);
      pa[2] = f2bf(v1[0]) | ((unsigned)f2bf(v1[1]) << 16);
      pa[3] = f2bf(v1[2]) | ((unsigned)f2bf(v1[3]) << 16);
      pb[0] = f2bf(v2[0]) | ((unsigned)f2bf(v2[1]) << 16);
      pb[1] = f2bf(v2[2]) | ((unsigned)f2bf(v2[3]) << 16);
      pb[2] = f2bf(v3[0]) | ((unsigned)f2bf(v3[1]) << 16);
      pb[3] = f2bf(v3[2]) | ((unsigned)f2bf(v3[3]) << 16);
      *(u32x4*)&As[ar * ASTR + ah] = pa;
      *(u32x4*)&As[ar * ASTR + ah + 8] = pb;
    } else {
      const unsigned short* Ab = (const unsigned short*)Ap;
      const unsigned short* srcb = Ab + (size_t)m0 * D_MODEL + k0;
#pragma unroll
      for (int p = 0; p < 2; ++p) {
        const int e = wid * 512 + p * 2048 + lane * 8;
        gl_lds16(srcb + (size_t)(e >> 5) * D_MODEL + (e & 31),
                 (char*)As + wid * 1024 + p * 4096);
      }
    }
    {
      const unsigned short* srcb = Bw + (size_t)n0 * D_MODEL + k0;
#pragma unroll
      for (int p = 0; p < 2; ++p) {
        const int e = wid * 512 + p * 2048 + lane * 8;
        gl_lds16(srcb + (size_t)(e >> 5) * D_MODEL + (e & 31),
                 (char*)Bs + wid * 1024 + p * 4096);
      }
    }
    __syncthreads();

    bf16x8 af[4], bfr[4];
#pragma unroll
    for (int i = 0; i < 4; ++i) {
      af[i]  = *(const bf16x8*)&As[(wrow + i * 16 + l16) * ASTR + lg * 8];
      bfr[i] = *(const bf16x8*)&Bs[(wcol + i * 16 + l16) * 32 + lg * 8];
    }
#pragma unroll
    for (int i = 0; i < 4; ++i)
#pragma unroll
      for (int j = 0; j < 4; ++j)
        acc[i][j] = __builtin_amdgcn_mfma_f32_16x16x32_bf16(af[i], bfr[j], acc[i][j], 0, 0, 0);
  }

#pragma unroll
  for (int j = 0; j < 4; ++j) {
    const int col = n0 + wcol + j * 16 + l16;
    const float bv = bias[col];
    if constexpr (OUT_MODE == 2) {
      const int hh = col >> 6, dd = col & 63;
#pragma unroll
      for (int i = 0; i < 4; ++i) {
        const int row0 = m0 + wrow + i * 16 + lg * 4;
        u32x2 pw;
        pw[0] = f2bf(acc[i][j][0] + bv) | ((unsigned)f2bf(acc[i][j][1] + bv) << 16);
        pw[1] = f2bf(acc[i][j][2] + bv) | ((unsigned)f2bf(acc[i][j][3] + bv) << 16);
        unsigned short* dst = (unsigned short*)Outp +
            ((((size_t)(row0 >> 11) * HEADS + hh) * DK + dd) * SEQ + (row0 & (SEQ - 1)));
        *(u32x2*)dst = pw;
      }
    } else {
#pragma unroll
      for (int i = 0; i < 4; ++i) {
        const int row0 = m0 + wrow + i * 16 + lg * 4;
#pragma unroll
        for (int r = 0; r < 4; ++r) {
          const float y = acc[i][j][r] + bv;
          if constexpr (OUT_MODE == 1)
            ((float*)Outp)[(size_t)(row0 + r) * D_MODEL + col] = y;
          else
            ((unsigned short*)Outp)[(size_t)(row0 + r) * D_MODEL + col] = f2bf(y);
        }
      }
    }
  }
}

// ---------------- flash attention v3: 1 wave/block, no barriers, direct-global K/V ----------------
// Grid: 4096 blocks = 64 q-chunks x 64 (b,h); each block = 1 wave, 32 q-rows.
__global__ __launch_bounds__(64, 3) void attn_v3(const unsigned short* __restrict__ Qb,
                                                 const unsigned short* __restrict__ Kb,
                                                 const unsigned short* __restrict__ Vtg,
                                                 unsigned short* __restrict__ Xo) {
  __shared__ unsigned short Ps[32 * 72];  // per-wave P [q][t]

  const int lane = threadIdx.x & 63;
  const int l16 = lane & 15, lg = lane >> 4;

  // XCD-pinning swizzle: physical p -> logical lb; XCD p%8 owns bh in [xcd*8, xcd*8+8)
  const int p = blockIdx.x;
  const int lb = (p & 7) * 512 + (p >> 3);
  const int qq = lb & 63, bh = lb >> 6;  // qq: 32-row chunk index
  const int b = bh >> 4, h = bh & 15;

  const size_t srow0 = (size_t)b * SEQ + qq * 32;
  const unsigned short* Qp = Qb + srow0 * D_MODEL + h * DK;
  const unsigned short* Kp = Kb + (size_t)b * SEQ * D_MODEL + h * DK;
  const unsigned short* Vp = Vtg + (size_t)bh * DK * SEQ;

  // Q fragments (B-operand): q = qf*16 + l16, k = kh*32 + lg*8
  bf16x8 qfrag[2][2];
#pragma unroll
  for (int qf = 0; qf < 2; ++qf)
#pragma unroll
    for (int kh = 0; kh < 2; ++kh)
      qfrag[qf][kh] = *(const bf16x8*)(Qp + (size_t)(qf * 16 + l16) * D_MODEL + kh * 32 + lg * 8);

  float mrun[2], lrun[2];
  f32x4 acco[2][4];
  const f32x4 zero = {0.f, 0.f, 0.f, 0.f};
#pragma unroll
  for (int qf = 0; qf < 2; ++qf) {
    mrun[qf] = -1e30f; lrun[qf] = 0.f;
#pragma unroll
    for (int df = 0; df < 4; ++df) acco[qf][df] = zero;
  }

  const float SC = 0.125f * 1.4426950408889634f;  // 1/sqrt(dk) * log2(e)
  const int srcbase = (lane & 48) | ((lane & 48) >> 2);

  // K fragments for kb=0
  bf16x8 kf[4][2];
#pragma unroll
  for (int tf = 0; tf < 4; ++tf)
#pragma unroll
    for (int kh = 0; kh < 2; ++kh)
      kf[tf][kh] = *(const bf16x8*)(Kp + (size_t)(tf * 16 + l16) * D_MODEL + kh * 32 + lg * 8);

#pragma unroll 1
  for (int kb = 0; kb < SEQ / 64; ++kb) {
    // QK^T swapped: sc[qf][tf] = S^T (rows t, cols q)
    f32x4 sc[2][4];
#pragma unroll
    for (int qf = 0; qf < 2; ++qf)
#pragma unroll
      for (int tf = 0; tf < 4; ++tf) sc[qf][tf] = zero;
    __builtin_amdgcn_s_setprio(1);
#pragma unroll
    for (int tf = 0; tf < 4; ++tf)
#pragma unroll
      for (int qf = 0; qf < 2; ++qf) {
        sc[qf][tf] = __builtin_amdgcn_mfma_f32_16x16x32_bf16(kf[tf][0], qfrag[qf][0], sc[qf][tf], 0, 0, 0);
        sc[qf][tf] = __builtin_amdgcn_mfma_f32_16x16x32_bf16(kf[tf][1], qfrag[qf][1], sc[qf][tf], 0, 0, 0);
      }
    __builtin_amdgcn_s_setprio(0);

    // V fragments (B-operand): col d = df*16+l16, k t = kh*32+lg*8 (latency hides under softmax)
    bf16x8 vf[4][2];
#pragma unroll
    for (int df = 0; df < 4; ++df)
#pragma unroll
      for (int kh = 0; kh < 2; ++kh)
        vf[df][kh] = *(const bf16x8*)(Vp + (size_t)(df * 16 + l16) * SEQ + kb * 64 + kh * 32 + lg * 8);

    // prefetch K fragments for kb+1 (latency hides under softmax + PV)
    if (kb + 1 < SEQ / 64) {
      const unsigned short* kn = Kp + (size_t)(kb + 1) * 64 * D_MODEL;
#pragma unroll
      for (int tf = 0; tf < 4; ++tf)
#pragma unroll
        for (int kh = 0; kh < 2; ++kh)
          kf[tf][kh] = *(const bf16x8*)(kn + (size_t)(tf * 16 + l16) * D_MODEL + kh * 32 + lg * 8);
    }

    // online softmax: lane owns column q = qf*16 + l16 (16 t-values in-lane)
#pragma unroll
    for (int qf = 0; qf < 2; ++qf) {
      float mx = fmaxf(fmaxf(sc[qf][0][0], sc[qf][0][1]), fmaxf(sc[qf][0][2], sc[qf][0][3]));
#pragma unroll
      for (int tf = 1; tf < 4; ++tf)
        mx = fmaxf(mx, fmaxf(fmaxf(sc[qf][tf][0], sc[qf][tf][1]),
                             fmaxf(sc[qf][tf][2], sc[qf][tf][3])));
      mx = fmaxf(mx, __shfl_xor(mx, 16));
      mx = fmaxf(mx, __shfl_xor(mx, 32));
      const float mxs = mx * SC;
      if (__ballot(mxs > mrun[qf] + 8.f)) {  // T13 defer-max
        const float mnew = fmaxf(mrun[qf], mxs);
        const float rs = __builtin_amdgcn_exp2f(mrun[qf] - mnew);
        mrun[qf] = mnew;
        lrun[qf] *= rs;
#pragma unroll
        for (int r = 0; r < 4; ++r) {
          const float rr = __shfl(rs, srcbase + r);
#pragma unroll
          for (int df = 0; df < 4; ++df) acco[qf][df][r] *= rr;
        }
      }
      const float m = mrun[qf];
      float sum = 0.f;
#pragma unroll
      for (int tf = 0; tf < 4; ++tf)
#pragma unroll
        for (int r = 0; r < 4; ++r) {
          const float pv = __builtin_amdgcn_exp2f(fmaf(sc[qf][tf][r], SC, -m));
          sc[qf][tf][r] = pv;
          sum += pv;
        }
      sum += __shfl_xor(sum, 16);
      sum += __shfl_xor(sum, 32);
      lrun[qf] += sum;
#pragma unroll
      for (int tf = 0; tf < 4; ++tf) {
        u32x2 pw;
        pw[0] = f2bf(sc[qf][tf][0]) | ((unsigned)f2bf(sc[qf][tf][1]) << 16);
        pw[1] = f2bf(sc[qf][tf][2]) | ((unsigned)f2bf(sc[qf][tf][3]) << 16);
        *(u32x2*)&Ps[(qf * 16 + l16) * 72 + tf * 16 + lg * 4] = pw;
      }
    }

    // P A-frags from per-wave LDS (in-wave lgkmcnt ordering, no barrier)
    bf16x8 pf[2][2];
#pragma unroll
    for (int qf = 0; qf < 2; ++qf)
#pragma unroll
      for (int k2 = 0; k2 < 2; ++k2)
        pf[qf][k2] = *(const bf16x8*)&Ps[(qf * 16 + l16) * 72 + k2 * 32 + lg * 8];

    // PV: O[q][d] += P[q][t] @ Vt[d][t]
    __builtin_amdgcn_s_setprio(1);
#pragma unroll
    for (int df = 0; df < 4; ++df)
#pragma unroll
      for (int qf = 0; qf < 2; ++qf) {
        acco[qf][df] = __builtin_amdgcn_mfma_f32_16x16x32_bf16(pf[qf][0], vf[df][0], acco[qf][df], 0, 0, 0);
        acco[qf][df] = __builtin_amdgcn_mfma_f32_16x16x32_bf16(pf[qf][1], vf[df][1], acco[qf][df], 0, 0, 0);
      }
    __builtin_amdgcn_s_setprio(0);
  }

  // finalize: /= l, store bf16 to X (layout [B*S, H*DK])
  unsigned short* dst = Xo + srow0 * D_MODEL + h * DK;
#pragma unroll
  for (int qf = 0; qf < 2; ++qf) {
    const float inv = 1.f / lrun[qf];
#pragma unroll
    for (int r = 0; r < 4; ++r) {
      const float rr = __shfl(inv, srcbase + r);
      const int row = qf * 16 + lg * 4 + r;
#pragma unroll
      for (int df = 0; df < 4; ++df)
        dst[(size_t)row * D_MODEL + df * 16 + l16] = f2bf(acco[qf][df][r] * rr);
    }
  }
}

extern "C" void kernel_launch(void* const* d_in, const int* in_sizes, int n_in,
                              void* d_out, int out_size, void* d_ws, size_t ws_size,
                              hipStream_t stream) {
  const float* query = (const float*)d_in[0];
  const float* key_  = (const float*)d_in[1];
  const float* value = (const float*)d_in[2];
  const float* Wq = (const float*)d_in[3];
  const float* bq = (const float*)d_in[4];
  const float* Wk = (const float*)d_in[5];
  const float* bk = (const float*)d_in[6];
  const float* Wv = (const float*)d_in[7];
  const float* bv = (const float*)d_in[8];
  const float* Wo = (const float*)d_in[9];
  const float* bo = (const float*)d_in[10];

  unsigned short* ws  = (unsigned short*)d_ws;
  unsigned short* WqB = ws;
  unsigned short* WkB = WqB + (1u << 20);
  unsigned short* WvB = WkB + (1u << 20);
  unsigned short* WoB = WvB + (1u << 20);
  unsigned short* Qb  = WoB + (1u << 20);
  unsigned short* Kb  = Qb + (size_t)MROWS * D_MODEL;
  unsigned short* Vtg = Kb + (size_t)MROWS * D_MODEL;  // [b][h][d][s]
  unsigned short* Xb  = Vtg + (size_t)MROWS * D_MODEL;
  if (ws_size < (size_t)(4u * (1u << 20) + 4u * (size_t)MROWS * D_MODEL) * 2u) return;

  cvt4<<<4096, 256, 0, stream>>>(Wq, Wk, Wv, Wo, WqB, WkB, WvB, WoB);

  gemm128<1, 0><<<512, 256, 0, stream>>>(query, WqB, bq, Qb);
  gemm128<1, 0><<<512, 256, 0, stream>>>(key_,  WkB, bk, Kb);
  gemm128<1, 2><<<512, 256, 0, stream>>>(value, WvB, bv, Vtg);  // writes V^T per head

  attn_v3<<<4096, 64, 0, stream>>>(Qb, Kb, Vtg, Xb);

  gemm128<0, 1><<<512, 256, 0, stream>>>(Xb, WoB, bo, (float*)d_out);
}